// Round 5
// baseline (236.009 us; speedup 1.0000x reference)
//
#include <hip/hip_runtime.h>
#include <stdint.h>

#define T_DIM 2048
#define B_DIM 128
#define H_DIM 128
#define QH_DIM 1024
#define NF 32
#define KW 31
#define TB 128                 // t's per block (4 waves x 32 t)
#define NTILE (T_DIM / TB)     // 16
#define CPAD_ROW (T_DIM + 32)

#define PREP_NB 512            // kA blocks doing mask/cpad prep (B*T/512)
#define G_NB 8                 // kA blocks doing Gt (8*512 >= KW*H)
#define QB_SEG 4               // QH split for the qb GEMV (512 blocks -> all CUs)

#define NEG_INF (-__builtin_inff())

typedef float v2f __attribute__((ext_vector_type(2)));

__device__ __forceinline__ float fast_tanh(float x) {
    float e = __expf(2.0f * x);
    return 1.0f - 2.0f * __builtin_amdgcn_rcpf(1.0f + e);
}

template <int C>
__device__ __forceinline__ float dpp_add(float x) {
    int m = __builtin_amdgcn_update_dpp(0, __float_as_int(x), C, 0xf, 0xf, true);
    return x + __int_as_float(m);
}
// full 64-lane sum; result lands wave-uniform (readlane -> SGPR)
__device__ __forceinline__ float wave_sum64(float x) {
    x = dpp_add<0x111>(x); x = dpp_add<0x112>(x); x = dpp_add<0x114>(x); x = dpp_add<0x118>(x);
    x = dpp_add<0x142>(x); x = dpp_add<0x143>(x);
    return __int_as_float(__builtin_amdgcn_readlane(__float_as_int(x), 63));
}

// kA: independent prep jobs fused into one launch.
//  blocks [0, PREP_NB)              : cpad/mbias prep
//  blocks [PREP_NB, +G_NB)          : Gt[k][h] = sum_f Wa[h,f]*conv_w[f,k]
//  blocks [PREP_NB+G_NB, +4*B_DIM)  : qb_part[seg][b][h] = quarter-dot of query.Wq
//                                     (4-way QH split -> 512 blocks -> all 256 CUs)
__global__ __launch_bounds__(512)
void kA_prep(const float* __restrict__ cum, const void* __restrict__ mask,
             float* __restrict__ cpad, float* __restrict__ mbias,
             const float* __restrict__ Wa, const float* __restrict__ conv_w,
             float* __restrict__ Gt,
             const float* __restrict__ query, const float* __restrict__ Wq,
             const float* __restrict__ bq, const float* __restrict__ conv_b,
             const float* __restrict__ ba, const float* __restrict__ score_b,
             float* __restrict__ qb_part) {
    const int bid = blockIdx.x;
    const int tid = threadIdx.x;

    if (bid < PREP_NB) {
        // ---- mask bias + padded cumulative-alignment row ----
        const int gid = bid * 512 + tid;       // B*T
        const int b = gid >> 11, t = gid & 2047;
        const int l = tid & 63;
        uint32_t u = ((const uint32_t*)mask)[l];
        unsigned long long hi = __ballot(u > 1u);
        unsigned long long nf = __ballot(u != 0u && u != 0x3f800000u);
        int layout = (hi == 0ull) ? 0 : ((nf == 0ull) ? 2 : 1);  // int32 / byte / float
        bool m;
        if (layout == 0)      m = ((const int32_t*)mask)[gid] != 0;
        else if (layout == 1) m = ((const uint8_t*)mask)[gid] != 0;
        else                  m = ((const float*)mask)[gid] != 0.0f;
        mbias[gid] = m ? NEG_INF : 0.0f;
        cpad[b * CPAD_ROW + 16 + t] = cum[gid];
        if (t < 16) cpad[b * CPAD_ROW + t] = 0.0f;
        else if (t >= T_DIM - 16) cpad[b * CPAD_ROW + 32 + t] = 0.0f;
    } else if (bid < PREP_NB + G_NB) {
        // ---- Gt[k][h] ----
        const int gid = (bid - PREP_NB) * 512 + tid;
        if (gid < KW * H_DIM) {
            const int k = gid >> 7, h = gid & 127;
            float acc = 0.0f;
            #pragma unroll
            for (int f = 0; f < NF; ++f) acc = fmaf(Wa[h * NF + f], conv_w[f * KW + k], acc);
            Gt[gid] = acc;
        }
    } else {
        // ---- qb_part[seg][b][h]: quarter of query[b,:].Wq[h,:] (QH slice of 256) ----
        const int qbid = bid - (PREP_NB + G_NB);
        const int b = qbid >> 2, seg = qbid & 3;
        const int h = tid & 127, sub = tid >> 7;    // 4 subs x 64 qh each
        __shared__ __align__(16) float qrow[256];
        __shared__ float partial[512];
        if (tid < 256) qrow[tid] = query[b * QH_DIM + seg * 256 + tid];
        __syncthreads();
        const float4* wq4 = (const float4*)(Wq + (size_t)h * QH_DIM + seg * 256 + sub * 64);
        const float4* q4 = (const float4*)(qrow + sub * 64);
        float acc = 0.0f;
        #pragma unroll
        for (int j = 0; j < 16; ++j) {
            float4 w = wq4[j], q = q4[j];
            acc += w.x * q.x + w.y * q.y + w.z * q.z + w.w * q.w;
        }
        partial[tid] = acc;
        __syncthreads();
        if (tid < 128) {
            float r = partial[h] + partial[h + 128] + partial[h + 256] + partial[h + 384];
            if (seg == 0) {
                float cb = bq[h] + ba[h] + score_b[h];
                #pragma unroll
                for (int f = 0; f < NF; ++f) cb = fmaf(Wa[h * NF + f], conv_b[f], cb);
                r += cb;
            }
            qb_part[(seg * B_DIM + b) * H_DIM + h] = r;
        }
    }
}

// k2: fused score + online softmax + context partials, single enc read.
// Wave = 32 t's of one b; lane = h-pair {2l, 2l+1}.
// G: 31 v2f in VGPRs (loaded once). Taps + mask bias: uniform s_loads (SGPRs).
// enc rows: DOUBLE-BUFFERED (chunk c+1's 8 loads issue before chunk c's compute
// consumes its registers -> 8 loads always in flight; k2 is enc-latency-bound).
// launch_bounds(256,3): cap 170 VGPR (G 62 + eeb 32 + state fits; no remat cliff).
__global__ __launch_bounds__(256, 3)
void k2_fused(const float* __restrict__ enc, const float* __restrict__ cpad,
              const float* __restrict__ mbias, const float* __restrict__ Gt,
              const float* __restrict__ qb_part, const float* __restrict__ score_w,
              float* __restrict__ s_out, float* __restrict__ o_part,
              float* __restrict__ ml_part) {
    const int b = blockIdx.x;      // b fastest: co-dispatched blocks read adjacent 512B
    const int tl = blockIdx.y;
    const int tid = threadIdx.x;
    const int l = tid & 63;
    const int wv = __builtin_amdgcn_readfirstlane(tid >> 6);
    const int tw0 = tl * TB + wv * 32;

    __shared__ float oc[4][H_DIM];
    __shared__ float mwl[4], lwl[4];

    v2f G[KW];                     // 62 VGPRs, lane-distinct, loaded once
    #pragma unroll
    for (int k = 0; k < KW; ++k) G[k] = *(const v2f*)(Gt + k * H_DIM + 2 * l);

    // combine the 4 qb partials (QH-split GEMV from kA)
    const float* qp = qb_part + b * H_DIM + 2 * l;
    v2f base = *(const v2f*)(qp);
    base += *(const v2f*)(qp + B_DIM * H_DIM);
    base += *(const v2f*)(qp + 2 * B_DIM * H_DIM);
    base += *(const v2f*)(qp + 3 * B_DIM * H_DIM);

    const v2f w2 = *(const v2f*)(score_w + 2 * l);
    const float* crow = cpad + b * CPAD_ROW;
    const float* mrow = mbias + b * T_DIM;
    const float* erow = enc + ((size_t)tw0 * B_DIM + b) * H_DIM + 2 * l;

    float m_w = NEG_INF, l_w = 0.0f;
    v2f o = {0.0f, 0.0f};
    float sv = 0.0f;

    v2f eeb[2][8];                 // double-buffered enc rows (32 VGPRs)
    #pragma unroll
    for (int it = 0; it < 8; ++it)
        eeb[0][it] = *(const v2f*)(erow + (size_t)it * B_DIM * H_DIM);

    #pragma unroll
    for (int c = 0; c < 4; ++c) {
        const int tb = tw0 + c * 8;

        // prefetch next chunk's enc rows while this chunk computes
        if (c < 3) {
            #pragma unroll
            for (int it = 0; it < 8; ++it)
                eeb[(c + 1) & 1][it] =
                    *(const v2f*)(erow + (size_t)(c * 8 + 8 + it) * B_DIM * H_DIM);
        }

        float sc[38];              // uniform -> SGPRs (transient per chunk)
        #pragma unroll
        for (int j = 0; j < 38; ++j) sc[j] = crow[tb + 1 + j];

        float su[8];
        #pragma unroll
        for (int it = 0; it < 8; ++it) {
            v2f acc = base;
            #pragma unroll
            for (int k = 0; k < KW; ++k)
                acc = __builtin_elementwise_fma(G[k], (v2f){sc[it + k], sc[it + k]}, acc);
            const v2f a2 = acc + eeb[c & 1][it];
            float p = w2.x * fast_tanh(a2.x) + w2.y * fast_tanh(a2.y);
            su[it] = wave_sum64(p) + mrow[tb + it];
        }

        // stash this chunk's (wave-uniform) scores into per-lane slots for output
        #pragma unroll
        for (int it = 0; it < 8; ++it) sv = (l == c * 8 + it) ? su[it] : sv;

        // online-softmax fold (enc rows still in registers)
        float m8 = su[0];
        #pragma unroll
        for (int it = 1; it < 8; ++it) m8 = fmaxf(m8, su[it]);
        const float m_new = fmaxf(m_w, m8);
        const float m_use = (m_new == NEG_INF) ? 0.0f : m_new;
        const float alpha = __expf(m_w - m_use);
        float lsum = 0.0f;
        v2f osum = {0.0f, 0.0f};
        #pragma unroll
        for (int it = 0; it < 8; ++it) {
            const float e = __expf(su[it] - m_use);
            lsum += e;
            osum = __builtin_elementwise_fma((v2f){e, e}, eeb[c & 1][it], osum);
        }
        l_w = fmaf(l_w, alpha, lsum);
        o = __builtin_elementwise_fma(o, (v2f){alpha, alpha}, osum);
        m_w = m_new;
    }

    if (l < 32) s_out[b * T_DIM + tw0 + l] = sv;

    // combine 4 waves -> per-tile (m, l, o[128])
    oc[wv][2 * l] = o.x;
    oc[wv][2 * l + 1] = o.y;
    if (l == 0) { mwl[wv] = m_w; lwl[wv] = l_w; }
    __syncthreads();
    if (tid < H_DIM) {
        const float mb = fmaxf(fmaxf(mwl[0], mwl[1]), fmaxf(mwl[2], mwl[3]));
        const float mu = (mb == NEG_INF) ? 0.0f : mb;
        const float b0 = __expf(mwl[0] - mu), b1 = __expf(mwl[1] - mu);
        const float b2 = __expf(mwl[2] - mu), b3 = __expf(mwl[3] - mu);
        const float ov = oc[0][tid] * b0 + oc[1][tid] * b1 + oc[2][tid] * b2 + oc[3][tid] * b3;
        const int tbase = b * NTILE + tl;
        o_part[tbase * H_DIM + tid] = ov;
        if (tid == 0) {
            ml_part[tbase * 2] = mb;
            ml_part[tbase * 2 + 1] = lwl[0] * b0 + lwl[1] * b1 + lwl[2] * b2 + lwl[3] * b3;
        }
    }
}

// k5: per-b global combine + alignment/cum epilogue. grid (B, 4):
// every seg recomputes the cheap (m,l) combine; seg 0 writes ctx;
// each seg handles T/4 of the alignment/cum rows.
__global__ __launch_bounds__(256)
void k5_final(float* __restrict__ s_align, const float* __restrict__ cum_in,
              float* __restrict__ cum_out, const float* __restrict__ o_part,
              const float* __restrict__ ml_part, float* __restrict__ ctx) {
    const int b = blockIdx.x, seg = blockIdx.y, tid = threadIdx.x;
    __shared__ float sm[NTILE], sl[NTILE], sb[NTILE];
    if (tid < NTILE) {
        sm[tid] = ml_part[(b * NTILE + tid) * 2];
        sl[tid] = ml_part[(b * NTILE + tid) * 2 + 1];
    }
    __syncthreads();
    float M = sm[0];
    #pragma unroll
    for (int i = 1; i < NTILE; ++i) M = fmaxf(M, sm[i]);
    const float M_use = (M == NEG_INF) ? 0.0f : M;
    if (tid < NTILE) sb[tid] = __expf(sm[tid] - M_use);
    __syncthreads();
    float L = 0.0f;
    #pragma unroll
    for (int i = 0; i < NTILE; ++i) L = fmaf(sl[i], sb[i], L);
    const float invL = 1.0f / L;
    if (seg == 0 && tid < H_DIM) {
        float ov = 0.0f;
        #pragma unroll
        for (int i = 0; i < NTILE; ++i)
            ov = fmaf(o_part[(b * NTILE + i) * H_DIM + tid], sb[i], ov);
        ctx[b * H_DIM + tid] = ov * invL;
    }
    #pragma unroll
    for (int j = 0; j < 2; ++j) {
        const int idx = b * T_DIM + seg * 512 + tid + j * 256;
        const float a = __expf(s_align[idx] - M_use) * invL;
        s_align[idx] = a;
        cum_out[idx] = cum_in[idx] + a;
    }
}

extern "C" void kernel_launch(void* const* d_in, const int* in_sizes, int n_in,
                              void* d_out, int out_size, void* d_ws, size_t ws_size,
                              hipStream_t stream) {
    const float* enc     = (const float*)d_in[0];
    const void*  mask    = d_in[1];
    const float* query   = (const float*)d_in[2];
    const float* cum     = (const float*)d_in[3];
    const float* conv_w  = (const float*)d_in[4];
    const float* conv_b  = (const float*)d_in[5];
    const float* Wq      = (const float*)d_in[6];
    const float* bq      = (const float*)d_in[7];
    const float* Wa      = (const float*)d_in[8];
    const float* ba      = (const float*)d_in[9];
    const float* score_w = (const float*)d_in[10];
    const float* score_b = (const float*)d_in[11];

    float* ctx_out   = (float*)d_out;                    // [B,H]
    float* cum_out   = ctx_out + B_DIM * H_DIM;          // [B,T]
    float* align_out = cum_out + B_DIM * T_DIM;          // [B,T]

    float* Gt      = (float*)d_ws;                       // [k][h] (pad 4096)
    float* qb_part = Gt + 4096;                          // [4][B][H]
    float* o_part  = qb_part + 4 * B_DIM * H_DIM;        // [B,NTILE,H]
    float* ml      = o_part + B_DIM * NTILE * H_DIM;     // [B,NTILE,2]
    float* cpad    = ml + 8192;                          // [B][T+32]
    float* mb      = cpad + B_DIM * CPAD_ROW;            // [B,T]

    kA_prep<<<PREP_NB + G_NB + QB_SEG * B_DIM, 512, 0, stream>>>(
        cum, mask, cpad, mb, Wa, conv_w, Gt,
        query, Wq, bq, conv_b, ba, score_b, qb_part);
    k2_fused<<<dim3(B_DIM, NTILE), 256, 0, stream>>>(enc, cpad, mb, Gt, qb_part, score_w,
                                                     align_out, o_part, ml);
    k5_final<<<dim3(B_DIM, 4), 256, 0, stream>>>(align_out, cum, cum_out, o_part, ml, ctx_out);
}

// Round 6
// 227.014 us; speedup vs baseline: 1.0396x; 1.0396x over previous
//
#include <hip/hip_runtime.h>
#include <stdint.h>

#define T_DIM 2048
#define B_DIM 128
#define H_DIM 128
#define QH_DIM 1024
#define NF 32
#define KW 31
#define TB 128                 // t's per block (4 waves x 32 t)
#define NTILE (T_DIM / TB)     // 16
#define CPAD_ROW (T_DIM + 32)

#define PREP_NB 512            // kA blocks doing mask/cpad prep (B*T/512)
#define G_NB 8                 // kA blocks doing Gt (8*512 >= KW*H)
#define QB_SEG 4               // QH split for the qb GEMV (512 blocks -> all CUs)

#define NEG_INF (-__builtin_inff())

typedef float v2f __attribute__((ext_vector_type(2)));

__device__ __forceinline__ float fast_tanh(float x) {
    float e = __expf(2.0f * x);
    return 1.0f - 2.0f * __builtin_amdgcn_rcpf(1.0f + e);
}

template <int C>
__device__ __forceinline__ float dpp_add(float x) {
    int m = __builtin_amdgcn_update_dpp(0, __float_as_int(x), C, 0xf, 0xf, true);
    return x + __int_as_float(m);
}
// full 64-lane sum; result lands wave-uniform (readlane -> SGPR)
__device__ __forceinline__ float wave_sum64(float x) {
    x = dpp_add<0x111>(x); x = dpp_add<0x112>(x); x = dpp_add<0x114>(x); x = dpp_add<0x118>(x);
    x = dpp_add<0x142>(x); x = dpp_add<0x143>(x);
    return __int_as_float(__builtin_amdgcn_readlane(__float_as_int(x), 63));
}

// kA: independent prep jobs fused into one launch.
//  blocks [0, PREP_NB)              : cpad/mbias prep
//  blocks [PREP_NB, +G_NB)          : Gt[k][h] = sum_f Wa[h,f]*conv_w[f,k]
//  blocks [PREP_NB+G_NB, +4*B_DIM)  : qb_part[seg][b][h] = quarter-dot of query.Wq
//                                     (4-way QH split -> 512 blocks -> all 256 CUs)
__global__ __launch_bounds__(512)
void kA_prep(const float* __restrict__ cum, const void* __restrict__ mask,
             float* __restrict__ cpad, float* __restrict__ mbias,
             const float* __restrict__ Wa, const float* __restrict__ conv_w,
             float* __restrict__ Gt,
             const float* __restrict__ query, const float* __restrict__ Wq,
             const float* __restrict__ bq, const float* __restrict__ conv_b,
             const float* __restrict__ ba, const float* __restrict__ score_b,
             float* __restrict__ qb_part) {
    const int bid = blockIdx.x;
    const int tid = threadIdx.x;

    if (bid < PREP_NB) {
        // ---- mask bias + padded cumulative-alignment row ----
        const int gid = bid * 512 + tid;       // B*T
        const int b = gid >> 11, t = gid & 2047;
        const int l = tid & 63;
        uint32_t u = ((const uint32_t*)mask)[l];
        unsigned long long hi = __ballot(u > 1u);
        unsigned long long nf = __ballot(u != 0u && u != 0x3f800000u);
        int layout = (hi == 0ull) ? 0 : ((nf == 0ull) ? 2 : 1);  // int32 / byte / float
        bool m;
        if (layout == 0)      m = ((const int32_t*)mask)[gid] != 0;
        else if (layout == 1) m = ((const uint8_t*)mask)[gid] != 0;
        else                  m = ((const float*)mask)[gid] != 0.0f;
        mbias[gid] = m ? NEG_INF : 0.0f;
        cpad[b * CPAD_ROW + 16 + t] = cum[gid];
        if (t < 16) cpad[b * CPAD_ROW + t] = 0.0f;
        else if (t >= T_DIM - 16) cpad[b * CPAD_ROW + 32 + t] = 0.0f;
    } else if (bid < PREP_NB + G_NB) {
        // ---- Gt[k][h] ----
        const int gid = (bid - PREP_NB) * 512 + tid;
        if (gid < KW * H_DIM) {
            const int k = gid >> 7, h = gid & 127;
            float acc = 0.0f;
            #pragma unroll
            for (int f = 0; f < NF; ++f) acc = fmaf(Wa[h * NF + f], conv_w[f * KW + k], acc);
            Gt[gid] = acc;
        }
    } else {
        // ---- qb_part[seg][b][h]: quarter of query[b,:].Wq[h,:] (QH slice of 256) ----
        const int qbid = bid - (PREP_NB + G_NB);
        const int b = qbid >> 2, seg = qbid & 3;
        const int h = tid & 127, sub = tid >> 7;    // 4 subs x 64 qh each
        __shared__ __align__(16) float qrow[256];
        __shared__ float partial[512];
        if (tid < 256) qrow[tid] = query[b * QH_DIM + seg * 256 + tid];
        __syncthreads();
        const float4* wq4 = (const float4*)(Wq + (size_t)h * QH_DIM + seg * 256 + sub * 64);
        const float4* q4 = (const float4*)(qrow + sub * 64);
        float acc = 0.0f;
        #pragma unroll
        for (int j = 0; j < 16; ++j) {
            float4 w = wq4[j], q = q4[j];
            acc += w.x * q.x + w.y * q.y + w.z * q.z + w.w * q.w;
        }
        partial[tid] = acc;
        __syncthreads();
        if (tid < 128) {
            float r = partial[h] + partial[h + 128] + partial[h + 256] + partial[h + 384];
            if (seg == 0) {
                float cb = bq[h] + ba[h] + score_b[h];
                #pragma unroll
                for (int f = 0; f < NF; ++f) cb = fmaf(Wa[h * NF + f], conv_b[f], cb);
                r += cb;
            }
            qb_part[(seg * B_DIM + b) * H_DIM + h] = r;
        }
    }
}

// k2: fused score + online softmax + context partials, single enc read.
// Wave = 32 t's of one b; lane = h-pair {2l, 2l+1}.
// G: 31 v2f in VGPRs (loaded once). Taps + mask bias: uniform s_loads (SGPRs).
// enc row: one coalesced b64 per t, consumed by score AND context fold while
// live in registers. Score reduce: DPP (VALU-only), result -> SGPR.
// launch_bounds(256,4): VGPR cap 128 -> 4 waves/SIMD (known-good codegen; any
// extra live v2f past this point triggers G rematerialization - do NOT add
// double-buffering here, measured twice as neutral-to-negative).
__global__ __launch_bounds__(256, 4)
void k2_fused(const float* __restrict__ enc, const float* __restrict__ cpad,
              const float* __restrict__ mbias, const float* __restrict__ Gt,
              const float* __restrict__ qb_part, const float* __restrict__ score_w,
              float* __restrict__ s_out, float* __restrict__ o_part,
              float* __restrict__ ml_part) {
    const int b = blockIdx.x;      // b fastest: co-dispatched blocks read adjacent 512B
    const int tl = blockIdx.y;
    const int tid = threadIdx.x;
    const int l = tid & 63;
    const int wv = __builtin_amdgcn_readfirstlane(tid >> 6);
    const int tw0 = tl * TB + wv * 32;

    __shared__ float oc[4][H_DIM];
    __shared__ float mwl[4], lwl[4];

    v2f G[KW];                     // 62 VGPRs, lane-distinct, loaded once
    #pragma unroll
    for (int k = 0; k < KW; ++k) G[k] = *(const v2f*)(Gt + k * H_DIM + 2 * l);

    // combine the 4 qb partials (QH-split GEMV from kA)
    const float* qp = qb_part + b * H_DIM + 2 * l;
    v2f base = *(const v2f*)(qp);
    base += *(const v2f*)(qp + B_DIM * H_DIM);
    base += *(const v2f*)(qp + 2 * B_DIM * H_DIM);
    base += *(const v2f*)(qp + 3 * B_DIM * H_DIM);

    const v2f w2 = *(const v2f*)(score_w + 2 * l);
    const float* crow = cpad + b * CPAD_ROW;
    const float* mrow = mbias + b * T_DIM;

    float m_w = NEG_INF, l_w = 0.0f;
    v2f o = {0.0f, 0.0f};
    float sv = 0.0f;

    #pragma unroll
    for (int c = 0; c < 4; ++c) {
        const int tb = tw0 + c * 8;

        float sc[38];              // uniform -> SGPRs (transient per chunk)
        #pragma unroll
        for (int j = 0; j < 38; ++j) sc[j] = crow[tb + 1 + j];

        v2f ee[8];
        #pragma unroll
        for (int it = 0; it < 8; ++it)
            ee[it] = *(const v2f*)(enc + ((size_t)(tb + it) * B_DIM + b) * H_DIM + 2 * l);

        float su[8];
        #pragma unroll
        for (int it = 0; it < 8; ++it) {
            v2f acc = base;
            #pragma unroll
            for (int k = 0; k < KW; ++k)
                acc = __builtin_elementwise_fma(G[k], (v2f){sc[it + k], sc[it + k]}, acc);
            const v2f a2 = acc + ee[it];
            float p = w2.x * fast_tanh(a2.x) + w2.y * fast_tanh(a2.y);
            su[it] = wave_sum64(p) + mrow[tb + it];
        }

        // stash this chunk's (wave-uniform) scores into per-lane slots for output
        #pragma unroll
        for (int it = 0; it < 8; ++it) sv = (l == c * 8 + it) ? su[it] : sv;

        // online-softmax fold (enc rows still in registers)
        float m8 = su[0];
        #pragma unroll
        for (int it = 1; it < 8; ++it) m8 = fmaxf(m8, su[it]);
        const float m_new = fmaxf(m_w, m8);
        const float m_use = (m_new == NEG_INF) ? 0.0f : m_new;
        const float alpha = __expf(m_w - m_use);
        float lsum = 0.0f;
        v2f osum = {0.0f, 0.0f};
        #pragma unroll
        for (int it = 0; it < 8; ++it) {
            const float e = __expf(su[it] - m_use);
            lsum += e;
            osum = __builtin_elementwise_fma((v2f){e, e}, ee[it], osum);
        }
        l_w = fmaf(l_w, alpha, lsum);
        o = __builtin_elementwise_fma(o, (v2f){alpha, alpha}, osum);
        m_w = m_new;
    }

    if (l < 32) s_out[b * T_DIM + tw0 + l] = sv;

    // combine 4 waves -> per-tile (m, l, o[128])
    oc[wv][2 * l] = o.x;
    oc[wv][2 * l + 1] = o.y;
    if (l == 0) { mwl[wv] = m_w; lwl[wv] = l_w; }
    __syncthreads();
    if (tid < H_DIM) {
        const float mb = fmaxf(fmaxf(mwl[0], mwl[1]), fmaxf(mwl[2], mwl[3]));
        const float mu = (mb == NEG_INF) ? 0.0f : mb;
        const float b0 = __expf(mwl[0] - mu), b1 = __expf(mwl[1] - mu);
        const float b2 = __expf(mwl[2] - mu), b3 = __expf(mwl[3] - mu);
        const float ov = oc[0][tid] * b0 + oc[1][tid] * b1 + oc[2][tid] * b2 + oc[3][tid] * b3;
        const int tbase = b * NTILE + tl;
        o_part[tbase * H_DIM + tid] = ov;
        if (tid == 0) {
            ml_part[tbase * 2] = mb;
            ml_part[tbase * 2 + 1] = lwl[0] * b0 + lwl[1] * b1 + lwl[2] * b2 + lwl[3] * b3;
        }
    }
}

// k5: per-b global combine + alignment/cum epilogue. grid (B, 4):
// every seg recomputes the cheap (m,l) combine; seg 0 writes ctx;
// each seg handles T/4 of the alignment/cum rows.
__global__ __launch_bounds__(256)
void k5_final(float* __restrict__ s_align, const float* __restrict__ cum_in,
              float* __restrict__ cum_out, const float* __restrict__ o_part,
              const float* __restrict__ ml_part, float* __restrict__ ctx) {
    const int b = blockIdx.x, seg = blockIdx.y, tid = threadIdx.x;
    __shared__ float sm[NTILE], sl[NTILE], sb[NTILE];
    if (tid < NTILE) {
        sm[tid] = ml_part[(b * NTILE + tid) * 2];
        sl[tid] = ml_part[(b * NTILE + tid) * 2 + 1];
    }
    __syncthreads();
    float M = sm[0];
    #pragma unroll
    for (int i = 1; i < NTILE; ++i) M = fmaxf(M, sm[i]);
    const float M_use = (M == NEG_INF) ? 0.0f : M;
    if (tid < NTILE) sb[tid] = __expf(sm[tid] - M_use);
    __syncthreads();
    float L = 0.0f;
    #pragma unroll
    for (int i = 0; i < NTILE; ++i) L = fmaf(sl[i], sb[i], L);
    const float invL = 1.0f / L;
    if (seg == 0 && tid < H_DIM) {
        float ov = 0.0f;
        #pragma unroll
        for (int i = 0; i < NTILE; ++i)
            ov = fmaf(o_part[(b * NTILE + i) * H_DIM + tid], sb[i], ov);
        ctx[b * H_DIM + tid] = ov * invL;
    }
    #pragma unroll
    for (int j = 0; j < 2; ++j) {
        const int idx = b * T_DIM + seg * 512 + tid + j * 256;
        const float a = __expf(s_align[idx] - M_use) * invL;
        s_align[idx] = a;
        cum_out[idx] = cum_in[idx] + a;
    }
}

extern "C" void kernel_launch(void* const* d_in, const int* in_sizes, int n_in,
                              void* d_out, int out_size, void* d_ws, size_t ws_size,
                              hipStream_t stream) {
    const float* enc     = (const float*)d_in[0];
    const void*  mask    = d_in[1];
    const float* query   = (const float*)d_in[2];
    const float* cum     = (const float*)d_in[3];
    const float* conv_w  = (const float*)d_in[4];
    const float* conv_b  = (const float*)d_in[5];
    const float* Wq      = (const float*)d_in[6];
    const float* bq      = (const float*)d_in[7];
    const float* Wa      = (const float*)d_in[8];
    const float* ba      = (const float*)d_in[9];
    const float* score_w = (const float*)d_in[10];
    const float* score_b = (const float*)d_in[11];

    float* ctx_out   = (float*)d_out;                    // [B,H]
    float* cum_out   = ctx_out + B_DIM * H_DIM;          // [B,T]
    float* align_out = cum_out + B_DIM * T_DIM;          // [B,T]

    float* Gt      = (float*)d_ws;                       // [k][h] (pad 4096)
    float* qb_part = Gt + 4096;                          // [4][B][H]
    float* o_part  = qb_part + 4 * B_DIM * H_DIM;        // [B,NTILE,H]
    float* ml      = o_part + B_DIM * NTILE * H_DIM;     // [B,NTILE,2]
    float* cpad    = ml + 8192;                          // [B][T+32]
    float* mb      = cpad + B_DIM * CPAD_ROW;            // [B,T]

    kA_prep<<<PREP_NB + G_NB + QB_SEG * B_DIM, 512, 0, stream>>>(
        cum, mask, cpad, mb, Wa, conv_w, Gt,
        query, Wq, bq, conv_b, ba, score_b, qb_part);
    k2_fused<<<dim3(B_DIM, NTILE), 256, 0, stream>>>(enc, cpad, mb, Gt, qb_part, score_w,
                                                     align_out, o_part, ml);
    k5_final<<<dim3(B_DIM, 4), 256, 0, stream>>>(align_out, cum, cum_out, o_part, ml, ctx_out);
}